// Round 7
// baseline (323.416 us; speedup 1.0000x reference)
//
#include <hip/hip_runtime.h>
#include <hip/hip_bf16.h>
#include <stdint.h>

// x: (4,4096,4096) f32 ; W_kv/W_gate: (1024,4096) f32 ; ape: (4,1024)
// norm_w: (512,) ; freqs_cis: (1024,32,2) ; out: (4,1024,512) f32
#define M_ROWS 16384
#define N_COLS 2048
#define K_DIM  4096
#define NEGV   -1e30f

typedef __bf16 bfv8 __attribute__((ext_vector_type(8)));
typedef float  f32x4 __attribute__((ext_vector_type(4)));
typedef unsigned short u16;

static __device__ __forceinline__ u16 f32_to_bf16_rne(float f) {
  union { float f; unsigned int u; } v; v.f = f;
  unsigned int u = v.u;
  u += 0x7fffu + ((u >> 16) & 1u);
  return (u16)(u >> 16);
}

static __device__ __forceinline__ float b2f(u16 b) {
  union { unsigned int u; float f; } v; v.u = ((unsigned int)b) << 16;
  return v.f;
}

// ---------- conversion: x f32 -> bf16 bits ----------
__global__ __launch_bounds__(256) void k_cvt_x(const float* __restrict__ in,
                                               u16* __restrict__ out, long n) {
  long i = (long)blockIdx.x * blockDim.x + threadIdx.x;
  long base = i * 8;
  if (base >= n) return;
  float4 a = *(const float4*)(in + base);
  float4 b = *(const float4*)(in + base + 4);
  union { u16 s[8]; uint4 v; } o;
  o.s[0] = f32_to_bf16_rne(a.x); o.s[1] = f32_to_bf16_rne(a.y);
  o.s[2] = f32_to_bf16_rne(a.z); o.s[3] = f32_to_bf16_rne(a.w);
  o.s[4] = f32_to_bf16_rne(b.x); o.s[5] = f32_to_bf16_rne(b.y);
  o.s[6] = f32_to_bf16_rne(b.z); o.s[7] = f32_to_bf16_rne(b.w);
  *(uint4*)(out + base) = o.v;
}

__global__ __launch_bounds__(256) void k_cvt_w(const float* __restrict__ wkv,
                                               const float* __restrict__ wg,
                                               u16* __restrict__ out) {
  long i = (long)blockIdx.x * blockDim.x + threadIdx.x;
  long base = i * 8;
  const float* src = (base < 4194304L) ? (wkv + base) : (wg + (base - 4194304L));
  float4 a = *(const float4*)(src);
  float4 b = *(const float4*)(src + 4);
  union { u16 s[8]; uint4 v; } o;
  o.s[0] = f32_to_bf16_rne(a.x); o.s[1] = f32_to_bf16_rne(a.y);
  o.s[2] = f32_to_bf16_rne(a.z); o.s[3] = f32_to_bf16_rne(a.w);
  o.s[4] = f32_to_bf16_rne(b.x); o.s[5] = f32_to_bf16_rne(b.y);
  o.s[6] = f32_to_bf16_rne(b.z); o.s[7] = f32_to_bf16_rne(b.w);
  *(uint4*)(out + base) = o.v;
}

// ---------- GEMM: 256x256 tile, BK=64, 4 waves (wave-tile 128x128), read-ahead ----------
// A: 16384x4096 bf16, B: 2048x4096 bf16, C = A.B^T (bf16).
// LDS (u16 idx): A[buf][kk] at buf*16384 + kk*8192 ; B at +32768.
// Line l (128B) = rows {2l,2l+1}; 16B-granule G' = (((row&1)<<2)|g) ^ (l&7).
// Phase = one kk-half: 16 ds_read (NEXT phase's frags) + 8 gld_lds (stage) interleaved
// 1:4 with 64 MFMA on CURRENT frags; vmcnt(8) at phase end retires the stage group
// issued 2 phases earlier. Barriers at phase END make stage-vs-read races impossible
// (passing BAR implies the phase's MFMAs — and thus the prior reads' lgkm — executed).
#define GLD16(g, l) __builtin_amdgcn_global_load_lds( \
    (const __attribute__((address_space(1))) unsigned int*)(g), \
    (__attribute__((address_space(3))) unsigned int*)(l), 16, 0, 0)

#define SB0 __builtin_amdgcn_sched_barrier(0)
#define BAR __builtin_amdgcn_s_barrier()
#define VM8 asm volatile("s_waitcnt vmcnt(8)" ::: "memory")

__global__ __launch_bounds__(256, 1) void k_gemm(const u16* __restrict__ A,
                                                 const u16* __restrict__ B,
                                                 u16* __restrict__ C) {
  __shared__ u16 lds[65536]; // 128 KiB

  const int tid  = threadIdx.x;
  const int wid  = tid >> 6;
  const int lane = tid & 63;
  const int wr = wid >> 1, wc = wid & 1;   // 2x2 wave grid; wave tile 128x128
  const int fr = lane & 15, fq = lane >> 4;

  // XCD-aware swizzle: grid 512 = 64 bm x 8 bn
  int o = blockIdx.x;
  int swz = (o & 7) * 64 + (o >> 3);
  const int bm = swz >> 3, bn = swz & 7;
  const int gm0 = bm << 8, gn0 = bn << 8;

  // fragment ds_read offsets (u16 units) within a kk-half region
  int aoff[8], boff[8];
#pragma unroll
  for (int mi = 0; mi < 8; ++mi) {
    int row = (wr << 7) + (mi << 4) + fr;
    int Gp = (((row & 1) << 2) | fq) ^ ((row >> 1) & 7);
    aoff[mi] = (row >> 1) * 64 + Gp * 8;
  }
#pragma unroll
  for (int ni = 0; ni < 8; ++ni) {
    int row = (wc << 7) + (ni << 4) + fr;
    int Gp = (((row & 1) << 2) | fq) ^ ((row >> 1) & 7);
    boff[ni] = (row >> 1) * 64 + Gp * 8;
  }

  // staging (256 thr): slot sp = j*256+tid ; inverse-swizzled global source
  const u16* pAs[4]; const u16* pBs[4]; int stgoff[4];
#pragma unroll
  for (int j = 0; j < 4; ++j) {
    int sp = j * 256 + tid;
    int l = sp >> 3, G = (sp & 7) ^ (l & 7);
    int r = 2 * l + (G >> 2), g = (G & 3) << 3;
    pAs[j] = A + ((size_t)(gm0 + r) << 12) + g;
    pBs[j] = B + ((size_t)(gn0 + r) << 12) + g;
    stgoff[j] = j * 2048 + (wid << 9); // wave-uniform dest (u16); HW adds lane*16B
  }

#define STG_A(Q, KK, J, KTN) GLD16(pAs[J] + (KTN) + (KK) * 32, &lds[(Q) * 16384 + (KK) * 8192 + stgoff[J]])
#define STG_B(Q, KK, J, KTN) GLD16(pBs[J] + (KTN) + (KK) * 32, &lds[32768 + (Q) * 16384 + (KK) * 8192 + stgoff[J]])
#define LDA(P, KK, MI) (*(const bfv8*)&lds[(P) * 16384 + (KK) * 8192 + aoff[MI]])
#define LDB(P, KK, NI) (*(const bfv8*)&lds[32768 + (P) * 16384 + (KK) * 8192 + boff[NI]])
#define MFM(MI, NI, Si) acc[MI][NI] = __builtin_amdgcn_mfma_f32_16x16x32_bf16(fa[Si][MI], fb[Si][NI], acc[MI][NI], 0, 0, 0)

// unit g: 1 ds_read (next-phase frag) + (g even: 1 stage gld) + 4 MFMA (current set)
#define UNIT(g, Pn, KKn, NSi, Si, STQ, STKK, KTN) do { \
  if ((g) < 8) { fa[NSi][(g)] = LDA(Pn, KKn, (g)); } \
  else         { fb[NSi][(g) - 8] = LDB(Pn, KKn, (g) - 8); } \
  if (((g) & 1) == 0) { \
    if ((g) < 8) { STG_A(STQ, STKK, (g) >> 1, KTN); } \
    else         { STG_B(STQ, STKK, ((g) - 8) >> 1, KTN); } } \
  MFM((g) >> 1, (((g) & 1) << 2) + 0, Si); \
  MFM((g) >> 1, (((g) & 1) << 2) + 1, Si); \
  MFM((g) >> 1, (((g) & 1) << 2) + 2, Si); \
  MFM((g) >> 1, (((g) & 1) << 2) + 3, Si); \
  SB0; \
} while (0)

#define PHASE(Pn, KKn, NSi, Si, STQ, STKK, KTN) do { \
  UNIT( 0, Pn, KKn, NSi, Si, STQ, STKK, KTN); \
  UNIT( 1, Pn, KKn, NSi, Si, STQ, STKK, KTN); \
  UNIT( 2, Pn, KKn, NSi, Si, STQ, STKK, KTN); \
  UNIT( 3, Pn, KKn, NSi, Si, STQ, STKK, KTN); \
  UNIT( 4, Pn, KKn, NSi, Si, STQ, STKK, KTN); \
  UNIT( 5, Pn, KKn, NSi, Si, STQ, STKK, KTN); \
  UNIT( 6, Pn, KKn, NSi, Si, STQ, STKK, KTN); \
  UNIT( 7, Pn, KKn, NSi, Si, STQ, STKK, KTN); \
  UNIT( 8, Pn, KKn, NSi, Si, STQ, STKK, KTN); \
  UNIT( 9, Pn, KKn, NSi, Si, STQ, STKK, KTN); \
  UNIT(10, Pn, KKn, NSi, Si, STQ, STKK, KTN); \
  UNIT(11, Pn, KKn, NSi, Si, STQ, STKK, KTN); \
  UNIT(12, Pn, KKn, NSi, Si, STQ, STKK, KTN); \
  UNIT(13, Pn, KKn, NSi, Si, STQ, STKK, KTN); \
  UNIT(14, Pn, KKn, NSi, Si, STQ, STKK, KTN); \
  UNIT(15, Pn, KKn, NSi, Si, STQ, STKK, KTN); \
  VM8; BAR; SB0; \
} while (0)

  f32x4 acc[8][8];
#pragma unroll
  for (int i = 0; i < 8; ++i)
#pragma unroll
    for (int j = 0; j < 8; ++j) acc[i][j] = (f32x4){0.f, 0.f, 0.f, 0.f};

  bfv8 fa[2][8], fb[2][8];

  // prologue: stage t0.kk0(8), t0.kk1(8), t1.kk0(8); vmcnt(8) retires t0 fully.
#pragma unroll
  for (int j = 0; j < 4; ++j) STG_A(0, 0, j, 0);
#pragma unroll
  for (int j = 0; j < 4; ++j) STG_B(0, 0, j, 0);
#pragma unroll
  for (int j = 0; j < 4; ++j) STG_A(0, 1, j, 0);
#pragma unroll
  for (int j = 0; j < 4; ++j) STG_B(0, 1, j, 0);
#pragma unroll
  for (int j = 0; j < 4; ++j) STG_A(1, 0, j, 64);
#pragma unroll
  for (int j = 0; j < 4; ++j) STG_B(1, 0, j, 64);
  SB0; VM8; BAR; SB0;
  // reads (t0, kk0) -> set0
#pragma unroll
  for (int g = 0; g < 8; ++g) { fa[0][g] = LDA(0, 0, g); fb[0][g] = LDB(0, 0, g); }

  for (int i = 0; i < 32; ++i) {
    const int ktB = ((2 * i + 1) & 63) << 6;
    const int ktC = ((2 * i + 2) & 63) << 6;
    const int ktD = ((2 * i + 3) & 63) << 6;
    // phase (2i,0):  MFMA set0 ; rd(buf0,kk1)->set1 ; stage buf1.kk1 (tile 2i+1)
    PHASE(0, 1, 1, 0, 1, 1, ktB);
    // phase (2i,1):  MFMA set1 ; rd(buf1,kk0)->set0 ; stage buf0.kk0 (tile 2i+2)
    PHASE(1, 0, 0, 1, 0, 0, ktC);
    // phase (2i+1,0): MFMA set0 ; rd(buf1,kk1)->set1 ; stage buf0.kk1 (tile 2i+2)
    PHASE(1, 1, 1, 0, 0, 1, ktC);
    // phase (2i+1,1): MFMA set1 ; rd(buf0,kk0)->set0 ; stage buf1.kk0 (tile 2i+3)
    PHASE(0, 0, 0, 1, 1, 0, ktD);
  }

  // epilogue: C/D layout col = lane&15, row = (lane>>4)*4 + reg ; store bf16
#pragma unroll
  for (int mi = 0; mi < 8; ++mi) {
    int row = gm0 + (wr << 7) + (mi << 4) + (fq << 2);
#pragma unroll
    for (int ni = 0; ni < 8; ++ni) {
      int col = gn0 + (wc << 7) + (ni << 4) + fr;
#pragma unroll
      for (int j = 0; j < 4; ++j)
        C[(size_t)(row + j) * N_COLS + col] = f32_to_bf16_rne(acc[mi][ni][j]);
    }
  }
#undef PHASE
#undef UNIT
#undef STG_A
#undef STG_B
#undef LDA
#undef LDB
#undef MFM
}

// ---------- pool + RMSNorm + RoPE + FWHT (bf16 input) ----------
__global__ __launch_bounds__(256) void k_pool(const u16* __restrict__ kvsc,  // 16384x2048 bf16
                                              const float* __restrict__ ape,
                                              const float* __restrict__ norm_w,
                                              const float* __restrict__ freqs,
                                              float* __restrict__ out) {
  __shared__ float sm[512];
  __shared__ float red[8];
  const int tid = threadIdx.x;
  const int bid = blockIdx.x;
  const int b = bid >> 10, ib = bid & 1023;

  float ss = 0.f;
#pragma unroll
  for (int cc = 0; cc < 2; ++cc) {
    int c = tid + (cc << 8);
    float kvv[8], scv[8];
    if (ib > 0) {
      size_t mb = ((size_t)b * 4096 + (size_t)(ib - 1) * 4);
#pragma unroll
      for (int p = 0; p < 4; ++p) {
        size_t ro = (mb + p) * N_COLS;
        kvv[p] = b2f(kvsc[ro + c]) + ape[p * 1024 + c];
        scv[p] = b2f(kvsc[ro + 1024 + c]);
      }
    } else {
#pragma unroll
      for (int p = 0; p < 4; ++p) { kvv[p] = 0.f; scv[p] = NEGV; }
    }
    size_t mb2 = ((size_t)b * 4096 + (size_t)ib * 4);
#pragma unroll
    for (int r = 0; r < 4; ++r) {
      size_t ro = (mb2 + r) * N_COLS;
      kvv[4 + r] = b2f(kvsc[ro + 512 + c]) + ape[r * 1024 + 512 + c];
      scv[4 + r] = b2f(kvsc[ro + 1024 + 512 + c]);
    }
    float mx = scv[0];
#pragma unroll
    for (int p = 1; p < 8; ++p) mx = fmaxf(mx, scv[p]);
    float se = 0.f, ac = 0.f;
#pragma unroll
    for (int p = 0; p < 8; ++p) {
      float e = __expf(scv[p] - mx);
      se += e; ac += e * kvv[p];
    }
    float pooled = ac / se;
    sm[c] = pooled;
    ss += pooled * pooled;
  }
#pragma unroll
  for (int m = 1; m < 64; m <<= 1) ss += __shfl_xor(ss, m, 64);
  if ((tid & 63) == 0) red[tid >> 6] = ss;
  __syncthreads();
  float sumsq = red[0] + red[1] + red[2] + red[3];
  float scale = rsqrtf(sumsq * (1.f / 512.f) + 1e-6f);
  sm[tid]       = sm[tid]       * scale * norm_w[tid];
  sm[tid + 256] = sm[tid + 256] * scale * norm_w[tid + 256];
  __syncthreads();
  if (tid < 32) {
    int j = tid;
    float xr = sm[448 + 2 * j], xi = sm[449 + 2 * j];
    float fr = freqs[((size_t)ib * 32 + j) * 2];
    float fi = freqs[((size_t)ib * 32 + j) * 2 + 1];
    sm[448 + 2 * j] = xr * fr - xi * fi;
    sm[449 + 2 * j] = xr * fi + xi * fr;
  }
  __syncthreads();
#pragma unroll
  for (int k = 0; k < 9; ++k) {
    int low = tid & ((1 << k) - 1);
    int i0 = ((tid >> k) << (k + 1)) | low;
    int i1 = i0 | (1 << k);
    float a = sm[i0], bb = sm[i1];
    sm[i0] = a + bb; sm[i1] = a - bb;
    __syncthreads();
  }
  const float OSC = 0.044194173824159216f; // 1/sqrt(512)
  size_t ob = (size_t)bid * 512;
  out[ob + tid]       = sm[tid] * OSC;
  out[ob + tid + 256] = sm[tid + 256] * OSC;
}

extern "C" void kernel_launch(void* const* d_in, const int* in_sizes, int n_in,
                              void* d_out, int out_size, void* d_ws, size_t ws_size,
                              hipStream_t stream) {
  const float* x      = (const float*)d_in[0];
  const float* W_kv   = (const float*)d_in[1];
  const float* W_gate = (const float*)d_in[2];
  const float* ape    = (const float*)d_in[3];
  const float* norm_w = (const float*)d_in[4];
  const float* freqs  = (const float*)d_in[5];
  float* out = (float*)d_out;

  char* ws = (char*)d_ws;
  u16* xb   = (u16*)ws;                                  // 134217728 B
  u16* wb   = (u16*)(ws + 134217728L);                   // 16777216 B
  u16* kvsc = (u16*)(ws + 134217728L + 16777216L);       // 67108864 B (bf16 C)

  hipLaunchKernelGGL(k_cvt_x, dim3(32768), dim3(256), 0, stream, x, xb, (long)67108864L);
  hipLaunchKernelGGL(k_cvt_w, dim3(4096), dim3(256), 0, stream, W_kv, W_gate, wb);
  hipLaunchKernelGGL(k_gemm, dim3(512), dim3(256), 0, stream, xb, wb, kvsc);
  hipLaunchKernelGGL(k_pool, dim3(4096), dim3(256), 0, stream, kvsc, ape, norm_w, freqs, out);
}